// Round 11
// baseline (655.791 us; speedup 1.0000x reference)
//
#include <hip/hip_runtime.h>
#include <hip/hip_cooperative_groups.h>
#include <math.h>

namespace cg = cooperative_groups;

#define B 4
#define T1 16
#define T2 16
#define SEG 4
#define V 8000
#define E 256
#define H 256
#define ENC 512
#define EOS 2
#define NEGV -1e30f
#define G4 1024
#define NCELL 1088
#define T21 17
#define MP 5504       // padded batched fc rows (43*128)
#define NTM 43        // fc m-tiles (128 rows)
#define NPART 126     // psum partials (63 nb * 2 wn)
#define GRID 256

typedef __attribute__((ext_vector_type(4))) float f32x4;
typedef __attribute__((ext_vector_type(8))) short bf16x8;

struct P {
    const int* y; const float* enc; const float* embed; const float* se;
    const float* phw; const float* phb; const float* pcw; const float* pcb;
    const float* wih0; const float* whh0; const float* b0;
    const float* wih1; const float* whh1; const float* b1;
    const float* fcw; const float* fcb;
    float *projhT, *projcT, *ctxT, *xT, *h0, *c0, *pre_ctxi, *pre_xi, *c1, *c2, *b1i;
    float *selbuf, *eospbuf, *psum;
    short *hc0, *hc1, *h2all, *whh0i, *w1i, *fcwbf;
    float* out;
};

__device__ __forceinline__ float sigm(float x) { return 1.f / (1.f + __expf(-x)); }
__device__ __forceinline__ float ftanh(float x) { float e = __expf(2.f * x); return 1.f - 2.f / (e + 1.f); }
__device__ __forceinline__ float b2f(short x) {
    unsigned u = ((unsigned)(unsigned short)x) << 16;
    return __builtin_bit_cast(float, u);
}
__device__ __forceinline__ short f2b(float f) {
    unsigned u = __builtin_bit_cast(unsigned, f);
    unsigned r = (u + 0x7fffu + ((u >> 16) & 1u)) >> 16;
    return (short)r;
}
__device__ __forceinline__ int swz8(int row) { return (row & 7) ^ ((row & 3) << 1); }

// ---- stage 64 rows x 512B into LDS (linear dest, inverse-swizzled source) ----
__device__ __forceinline__ void stage64(const char* g0, size_t gstrideB, int kOffB, char* lds) {
    int tid = threadIdx.x;
#pragma unroll
    for (int it = 0; it < 8; ++it) {
        int chunk = it * 256 + tid;
        int row = chunk >> 5;
        int g = chunk & 31;
        const char* src = g0 + (size_t)row * gstrideB + kOffB + ((g ^ swz8(row)) << 4);
        __builtin_amdgcn_global_load_lds((const __attribute__((address_space(1))) void*)src,
                                         (__attribute__((address_space(3))) void*)(lds + chunk * 16),
                                         16, 0, 0);
    }
}
__device__ __forceinline__ bf16x8 lds_frag(const char* lds, int row, int col16) {
    return *(const bf16x8*)(lds + row * 512 + ((col16 ^ swz8(row)) << 4));
}
// per-wave 16Mx64N x K=256 from staged [64][512B] tiles
__device__ __forceinline__ void mma_tile(const char* smA, const char* smB,
                                         int wave, int ln, int kg, f32x4 acc[4]) {
#pragma unroll
    for (int ks = 0; ks < 8; ++ks) {
        bf16x8 a = lds_frag(smA, wave * 16 + ln, ks * 4 + kg);
#pragma unroll
        for (int nf = 0; nf < 4; ++nf) {
            bf16x8 b = lds_frag(smB, nf * 16 + ln, ks * 4 + kg);
            acc[nf] = __builtin_amdgcn_mfma_f32_16x16x32_bf16(a, b, acc[nf], 0, 0, 0);
        }
    }
}
// 128-row x 256B-half tile read (fc)
__device__ __forceinline__ bf16x8 frag128(const char* lds, int row, int gl) {
    return *(const bf16x8*)(lds + row * 256 + ((gl ^ swz8(row)) << 4));
}

// ================= phase bodies =================

__device__ void phase_setup(const P& p) {
    int tid = threadIdx.x;
    for (int u = blockIdx.x; u < 3537; u += gridDim.x) {
        int bid = u;
        if (bid < 2000) {
            int i = (bid * 256 + tid) * 4;
            float4 v = *(const float4*)&p.fcw[i];
            short4 o = { f2b(v.x), f2b(v.y), f2b(v.z), f2b(v.w) };
            *(short4*)&p.fcwbf[i] = o;
            continue;
        }
        bid -= 2000;
        if (bid < 256) {
            int i = (bid * 256 + tid) * 4;
            int gp = i >> 8, k = i & 255;
            float4 v = *(const float4*)&p.whh0[(size_t)((gp & 3) * 256 + (gp >> 2)) * 256 + k];
            short4 o = { f2b(v.x), f2b(v.y), f2b(v.z), f2b(v.w) };
            *(short4*)&p.whh0i[i] = o;
            continue;
        }
        bid -= 256;
        if (bid < 512) {
            int i = (bid * 256 + tid) * 4;
            int gp = i >> 9, k = i & 511;
            int g = (gp & 3) * 256 + (gp >> 2);
            const float* src = (k < 256) ? &p.wih1[(size_t)g * 256 + k] : &p.whh1[(size_t)g * 256 + (k - 256)];
            float4 v = *(const float4*)src;
            short4 o = { f2b(v.x), f2b(v.y), f2b(v.z), f2b(v.w) };
            *(short4*)&p.w1i[i] = o;
            continue;
        }
        bid -= 512;
        if (bid < 128) {
            int i = (bid * 256 + tid) * 4;
            int k = i >> 8, r = i & 255;
            float4 o = { p.phw[(size_t)r * ENC + k], p.phw[(size_t)(r + 1) * ENC + k],
                         p.phw[(size_t)(r + 2) * ENC + k], p.phw[(size_t)(r + 3) * ENC + k] };
            *(float4*)&p.projhT[i] = o;
            continue;
        }
        bid -= 128;
        if (bid < 128) {
            int i = (bid * 256 + tid) * 4;
            int k = i >> 8, r = i & 255;
            float4 o = { p.pcw[(size_t)r * ENC + k], p.pcw[(size_t)(r + 1) * ENC + k],
                         p.pcw[(size_t)(r + 2) * ENC + k], p.pcw[(size_t)(r + 3) * ENC + k] };
            *(float4*)&p.projcT[i] = o;
            continue;
        }
        bid -= 128;
        if (bid < 512) {
            int i = (bid * 256 + tid) * 4;
            int g = i >> 9, k = i & 511;
            float4 v = *(const float4*)&p.wih0[i];
            float* base = (k < 256) ? &p.ctxT[(size_t)k * G4 + g] : &p.xT[(size_t)(k - 256) * G4 + g];
            base[0] = v.x; base[G4] = v.y; base[2 * G4] = v.z; base[3 * G4] = v.w;
            continue;
        }
        bid -= 512;
        if (bid < 1) {
            float4 o = { p.b1[tid], p.b1[256 + tid], p.b1[512 + tid], p.b1[768 + tid] };
            *(float4*)&p.b1i[tid * 4] = o;
        }
    }
}

__device__ void phase_init_state(const P& p, char* smem) {
    int bi = blockIdx.x;
    if (bi >= 64) return;
    float* eo = (float*)smem;
    int b = bi / T1, i = bi % T1;
    int j = threadIdx.x;
    for (int e = j; e < ENC; e += 256) eo[e] = p.enc[(size_t)(i * B + b) * ENC + e];
    __syncthreads();
    float ha = p.phb[j], ca = p.pcb[j];
    for (int e = 0; e < ENC; ++e) {
        float x = eo[e];
        ha += x * p.projhT[(size_t)e * H + j];
        ca += x * p.projcT[(size_t)e * H + j];
    }
    p.h0[(size_t)bi * H + j] = ha;
    p.c0[(size_t)bi * H + j] = ca;
}

__device__ void phase_init2(const P& p, char* smem) {
    float* sb = (float*)smem;
    int j = threadIdx.x;
    for (int u = blockIdx.x; u < NCELL + 64 + (SEG + 1) * B * T21; u += gridDim.x) {
        int bid = u;
        if (bid < NCELL) {
            int cell = bid, bi = cell / T21;
            p.c1[(size_t)cell * H + j] = p.c0[(size_t)bi * H + j];
            p.c2[(size_t)cell * H + j] = 0.f;
            p.hc0[(size_t)cell * 512 + j] = f2b(p.h0[(size_t)bi * H + j]);   // h1_{-1}
            p.hc1[(size_t)cell * 512 + 256 + j] = 0;                         // h2_{-1}
            continue;
        }
        bid -= NCELL;
        if (bid < 64) {
            int bi = bid;
            __syncthreads();
            sb[j] = p.h0[(size_t)bi * H + j];
            __syncthreads();
            float a0 = p.b0[j], a1 = p.b0[256 + j], a2 = p.b0[512 + j], a3 = p.b0[768 + j];
            for (int k = 0; k < H; ++k) {
                float x = sb[k];
                const float* w = p.ctxT + (size_t)k * G4;
                a0 += x * w[j]; a1 += x * w[256 + j]; a2 += x * w[512 + j]; a3 += x * w[768 + j];
            }
            *(float4*)&p.pre_ctxi[(size_t)bi * G4 + 4 * j] = make_float4(a0, a1, a2, a3);
            continue;
        }
        bid -= 64;
        int row = bid;                    // (s*B + b)*T21 + t
        int s = row / (B * T21), rem = row % (B * T21);
        int b = rem / T21, t = rem % T21;
        const float* src;
        if (s == 0) src = p.se;
        else { int tt = t + s - 1; if (tt > 15) tt = 15; src = p.embed + (size_t)p.y[b * T2 + tt] * E; }
        __syncthreads();
        sb[j] = src[j];
        __syncthreads();
        float a0 = 0, a1 = 0, a2 = 0, a3 = 0;
        for (int k = 0; k < E; ++k) {
            float x = sb[k];
            const float* w = p.xT + (size_t)k * G4;
            a0 += x * w[j]; a1 += x * w[256 + j]; a2 += x * w[512 + j]; a3 += x * w[768 + j];
        }
        *(float4*)&p.pre_xi[(size_t)row * G4 + 4 * j] = make_float4(a0, a1, a2, a3);
    }
}

// ---- LSTM epilogues (sg = 64x68 float scratch in LDS) ----
__device__ void epi_l0(const P& p, float* sg, f32x4 acc[4], int m0, int nb, int step, short* OUT) {
    int tid = threadIdx.x, wave = tid >> 6, lane = tid & 63, ln = lane & 15, kg = lane >> 4;
#pragma unroll
    for (int nf = 0; nf < 4; ++nf)
#pragma unroll
        for (int r = 0; r < 4; ++r)
            sg[(wave * 16 + kg * 4 + r) * 68 + nf * 16 + ln] = acc[nf][r];
    __syncthreads();
    int jlo = nb * 16;
#pragma unroll
    for (int q2 = 0; q2 < 4; ++q2) {
        int item = q2 * 256 + tid;
        int c = item >> 4, jj = item & 15;
        int cell = m0 + c;
        int j = jlo + jj;
        float4 g = *(float4*)&sg[c * 68 + 4 * jj];
        int bi = cell / T21;
        int bb = bi >> 4;
        int t = cell % T21;
        int prow = (step * B + bb) * T21 + t;
        float4 pc = *(const float4*)&p.pre_ctxi[(size_t)bi * G4 + 4 * j];
        float4 px = *(const float4*)&p.pre_xi[(size_t)prow * G4 + 4 * j];
        float ig = g.x + pc.x + px.x, fg = g.y + pc.y + px.y;
        float gg = g.z + pc.z + px.z, og = g.w + pc.w + px.w;
        float cold = p.c1[(size_t)cell * H + j];
        float cn = sigm(fg) * cold + sigm(ig) * ftanh(gg);
        float hn = sigm(og) * ftanh(cn);
        p.c1[(size_t)cell * H + j] = cn;
        OUT[(size_t)cell * 512 + j] = f2b(hn);
    }
    __syncthreads();
}

__device__ void epi_l1(const P& p, float* sg, f32x4 acc[4], int m0, int nb, int s, short* OUT, bool writeOUT) {
    int tid = threadIdx.x, wave = tid >> 6, lane = tid & 63, ln = lane & 15, kg = lane >> 4;
#pragma unroll
    for (int nf = 0; nf < 4; ++nf)
#pragma unroll
        for (int r = 0; r < 4; ++r)
            sg[(wave * 16 + kg * 4 + r) * 68 + nf * 16 + ln] = acc[nf][r];
    __syncthreads();
    short* slab = p.h2all + (size_t)(s + 1) * NCELL * 256;
    int jlo = nb * 16;
#pragma unroll
    for (int q2 = 0; q2 < 4; ++q2) {
        int item = q2 * 256 + tid;
        int c = item >> 4, jj = item & 15;
        int cell = m0 + c;
        int j = jlo + jj;
        float4 g = *(float4*)&sg[c * 68 + 4 * jj];
        float4 bv = *(const float4*)&p.b1i[4 * j];
        float ig = g.x + bv.x, fg = g.y + bv.y, gg = g.z + bv.z, og = g.w + bv.w;
        float cold = p.c2[(size_t)cell * H + j];
        float cn = sigm(fg) * cold + sigm(ig) * ftanh(gg);
        float hn = sigm(og) * ftanh(cn);
        p.c2[(size_t)cell * H + j] = cn;
        short hb = f2b(hn);
        slab[(size_t)cell * 256 + j] = hb;
        if (writeOUT) OUT[(size_t)cell * 512 + 256 + j] = hb;
    }
    __syncthreads();
}

// ---- lstm phase: block owns (mb,nb); B tiles resident across phases ----
// s1 = L1 step (-1 none), s0 = L0 step (-1 none). doB: stage resident B tiles.
__device__ void phase_lstm(const P& p, char* smem, int s1, int s0, bool doB) {
    int bx = blockIdx.x, tid = threadIdx.x;
    int wave = tid >> 6, lane = tid & 63, ln = lane & 15, kg = lane >> 4;
    int nb = bx & 15, mb = bx >> 4;
    char* A  = smem;
    char* B0 = smem + 32768;    // whh0 (K=256)
    char* B1 = smem + 65536;    // w1 kh0
    char* B2 = smem + 98304;    // w1 kh1
    if (doB) {
        stage64((const char*)(p.whh0i + (size_t)nb * 64 * 256), 512, 0, B0);
        stage64((const char*)(p.w1i + (size_t)nb * 64 * 512), 1024, 0, B1);
        stage64((const char*)(p.w1i + (size_t)nb * 64 * 512), 1024, 512, B2);
    }
    int sin = (s0 >= 0) ? s0 - 1 : s1;          // IN = H_sin
    const short* IN = ((sin + 1) & 1) ? p.hc1 : p.hc0;
    short* OUT = (sin & 1) ? p.hc1 : p.hc0;
    f32x4 acc1[4] = {}, acc0[4] = {};
    stage64((const char*)(IN + (size_t)mb * 64 * 512), 1024, 0, A);   // h1 half
    __syncthreads();
    if (s1 >= 0) mma_tile(A, B1, wave, ln, kg, acc1);
    if (s0 >= 0) mma_tile(A, B0, wave, ln, kg, acc0);
    __syncthreads();
    if (s1 >= 0) {
        stage64((const char*)(IN + (size_t)mb * 64 * 512), 1024, 512, A);  // h2 half
        __syncthreads();
        mma_tile(A, B2, wave, ln, kg, acc1);
        __syncthreads();
        epi_l1(p, (float*)A, acc1, mb * 64, nb, s1, OUT, s1 != SEG);
    }
    if (s0 >= 0)
        epi_l0(p, (float*)A, acc0, mb * 64, nb, s0, OUT);
    // extras: tile row mb=16
    if (s1 >= 0 && mb == 15) {
        f32x4 e1[4] = {};
        stage64((const char*)(IN + (size_t)1024 * 512), 1024, 0, A);
        __syncthreads();
        mma_tile(A, B1, wave, ln, kg, e1);
        __syncthreads();
        stage64((const char*)(IN + (size_t)1024 * 512), 1024, 512, A);
        __syncthreads();
        mma_tile(A, B2, wave, ln, kg, e1);
        __syncthreads();
        epi_l1(p, (float*)A, e1, 1024, nb, s1, OUT, s1 != SEG);
    }
    if (s0 >= 0 && mb == 14) {
        f32x4 e0[4] = {};
        stage64((const char*)(IN + (size_t)1024 * 512), 1024, 0, A);
        __syncthreads();
        mma_tile(A, B0, wave, ln, kg, e0);
        __syncthreads();
        epi_l0(p, (float*)A, e0, 1024, nb, s0, OUT);
    }
}

// ---- persistent fc: resident B band + double-buffered A ----
__device__ void phase_fc(const P& p, char* smem) {
    int bx = blockIdx.x, tid = threadIdx.x;
    char* Ab0 = smem;
    char* Ab1 = smem + 32768;
    char* Bh0 = smem + 65536;
    char* Bh1 = smem + 98304;
    int t6 = bx & 63, w2 = bx >> 6;
    int nb, w;
    if (t6 == 63) { nb = w2; w = 4; } else { nb = t6; w = w2; }
    int nw = (nb < 4) ? 5 : 4;
    int n0 = nb * 128;
    // stage resident B halves (vocab rows clamped; pad cols killed by fbn)
#pragma unroll
    for (int kh = 0; kh < 2; ++kh) {
        char* dst = kh ? Bh1 : Bh0;
#pragma unroll
        for (int it = 0; it < 8; ++it) {
            int chunk = it * 256 + tid;
            int row = chunk >> 4;
            int g = chunk & 15;
            int grow = n0 + row; if (grow > V - 1) grow = V - 1;
            const char* src = (const char*)(p.fcwbf + (size_t)grow * 256) + kh * 256 + ((g ^ swz8(row)) << 4);
            __builtin_amdgcn_global_load_lds((const __attribute__((address_space(1))) void*)src,
                                             (__attribute__((address_space(3))) void*)(dst + chunk * 16),
                                             16, 0, 0);
        }
    }
    int mbs[11]; int cnt = 0;
    for (int mb = w; mb < NTM; mb += nw) mbs[cnt++] = mb;
    const short* h2base = p.h2all + (size_t)NCELL * 256;
    auto stageA = [&](int mb, int kh, char* buf) {
#pragma unroll
        for (int it = 0; it < 8; ++it) {
            int chunk = it * 256 + tid;
            int row = chunk >> 4;
            int g = chunk & 15;
            const char* src = (const char*)(h2base + (size_t)(mb * 128 + row) * 256) + kh * 256 + ((g ^ swz8(row)) << 4);
            __builtin_amdgcn_global_load_lds((const __attribute__((address_space(1))) void*)src,
                                             (__attribute__((address_space(3))) void*)(buf + chunk * 16),
                                             16, 0, 0);
        }
    };
    stageA(mbs[0], 0, Ab0);
    __syncthreads();
    int wave = tid >> 6, lane = tid & 63, ln = lane & 15, kg = lane >> 4;
    int wm = wave >> 1, wn = wave & 1;
    f32x4 acc[4][4] = {};
    int nst = cnt * 2;
    for (int st = 0; st < nst; ++st) {
        int mb = mbs[st >> 1], kh = st & 1;
        if (st + 1 < nst) stageA(mbs[(st + 1) >> 1], (st + 1) & 1, ((st + 1) & 1) ? Ab1 : Ab0);
        char* Acur = (st & 1) ? Ab1 : Ab0;
        char* Bcur = kh ? Bh1 : Bh0;
#pragma unroll
        for (int ks = 0; ks < 4; ++ks) {
            bf16x8 a[4], b[4];
#pragma unroll
            for (int mf = 0; mf < 4; ++mf) a[mf] = frag128(Acur, wm * 64 + mf * 16 + ln, ks * 4 + kg);
#pragma unroll
            for (int nf = 0; nf < 4; ++nf) b[nf] = frag128(Bcur, wn * 64 + nf * 16 + ln, ks * 4 + kg);
#pragma unroll
            for (int mf = 0; mf < 4; ++mf)
#pragma unroll
                for (int nf = 0; nf < 4; ++nf)
                    acc[mf][nf] = __builtin_amdgcn_mfma_f32_16x16x32_bf16(a[mf], b[nf], acc[mf][nf], 0, 0, 0);
        }
        if (kh) {
            int m0 = mb * 128;
            float rs[4][4];
#pragma unroll
            for (int mf = 0; mf < 4; ++mf)
#pragma unroll
                for (int r2 = 0; r2 < 4; ++r2) rs[mf][r2] = 0.f;
#pragma unroll
            for (int nf = 0; nf < 4; ++nf) {
                int col = n0 + wn * 64 + nf * 16 + ln;
                float fbn = (col < V) ? p.fcb[col] : NEGV;
#pragma unroll
                for (int mf = 0; mf < 4; ++mf)
#pragma unroll
                    for (int r2 = 0; r2 < 4; ++r2)
                        rs[mf][r2] += __expf(acc[mf][nf][r2] + fbn);
            }
#pragma unroll
            for (int mask = 1; mask < 16; mask <<= 1)
#pragma unroll
                for (int mf = 0; mf < 4; ++mf)
#pragma unroll
                    for (int r2 = 0; r2 < 4; ++r2)
                        rs[mf][r2] += __shfl_xor(rs[mf][r2], mask);
            if (ln == 0) {
#pragma unroll
                for (int mf = 0; mf < 4; ++mf)
#pragma unroll
                    for (int r2 = 0; r2 < 4; ++r2)
                        p.psum[(size_t)(nb * 2 + wn) * MP + m0 + wm * 64 + mf * 16 + kg * 4 + r2] = rs[mf][r2];
            }
#pragma unroll
            for (int mf = 0; mf < 4; ++mf)
#pragma unroll
                for (int nf = 0; nf < 4; ++nf)
                    acc[mf][nf] = f32x4{0.f, 0.f, 0.f, 0.f};
        }
        __syncthreads();
    }
}

__device__ void phase_combine(const P& p) {
    int cb = blockIdx.x;
    if (cb >= 85) return;
    int s = cb / 17, blk = cb % 17;
    int tid = threadIdx.x;
    int cl = tid >> 2, q = tid & 3;
    int cell = blk * 64 + cl;
    int b = cell / (T1 * T21);
    int t = cell % T21;
    int tv = 0;
    if (s < SEG) { int tt = t + s; if (tt > 15) tt = 15; tv = p.y[b * T2 + tt]; }
    const short* hp = p.h2all + (size_t)(s + 1) * NCELL * 256 + (size_t)cell * 256 + q * 64;
    const short* w1 = p.fcwbf + (size_t)tv * 256 + q * 64;
    const short* w2 = p.fcwbf + (size_t)EOS * 256 + q * 64;
    float d1 = 0.f, d2 = 0.f;
#pragma unroll
    for (int u = 0; u < 8; ++u) {
        bf16x8 av  = *(const bf16x8*)(hp + u * 8);
        bf16x8 wv1 = *(const bf16x8*)(w1 + u * 8);
        bf16x8 wv2 = *(const bf16x8*)(w2 + u * 8);
#pragma unroll
        for (int e = 0; e < 8; ++e) {
            float a = b2f(av[e]);
            d1 += a * b2f(wv1[e]);
            d2 += a * b2f(wv2[e]);
        }
    }
    d1 += __shfl_xor(d1, 1); d1 += __shfl_xor(d1, 2);
    d2 += __shfl_xor(d2, 1); d2 += __shfl_xor(d2, 2);
    int col = s * NCELL + cell;
    float ss = 0.f;
    for (int v2 = q * 32; v2 < q * 32 + 32 && v2 < NPART; ++v2)
        ss += p.psum[(size_t)v2 * MP + col];
    ss += __shfl_xor(ss, 1); ss += __shfl_xor(ss, 2);
    if (q == 0) {
        float lse = __logf(ss);
        p.selbuf[s * NCELL + cell]  = d1 + p.fcb[tv]  - lse;
        p.eospbuf[s * NCELL + cell] = d2 + p.fcb[EOS] - lse;
    }
}

__device__ void phase_dp(const P& p, char* smem) {
    if (blockIdx.x != 0) return;
    float* row = (float*)smem;                         // [5][1088]
    float* alpha = (float*)(smem + (SEG + 1) * NCELL * 4);  // [4][17]
    int tid = threadIdx.x;
    for (int c = tid; c < NCELL; c += 256) {
        float cum = 0.f;
        row[c] = p.eospbuf[c];
#pragma unroll
        for (int j = 1; j <= SEG; ++j) {
            cum += p.selbuf[(j - 1) * NCELL + c];
            row[j * NCELL + c] = cum + p.eospbuf[j * NCELL + c];
        }
    }
    int b = tid / T21, t = tid % T21;
    bool act = tid < B * T21;
    if (act) alpha[b * T21 + t] = (t == 0) ? 0.f : NEGV;
    __syncthreads();
    for (int i = 0; i < T1; ++i) {
        float val = NEGV;
        if (act) {
            float terms[SEG + 1];
            float mx = -3.4e38f;
            int cnt2 = 0;
            for (int j = 0; j <= SEG && j <= t; ++j) {
                int cell = (b * T1 + i) * T21 + (t - j);
                float term = alpha[b * T21 + t - j] + row[j * NCELL + cell];
                terms[cnt2++] = term;
                mx = fmaxf(mx, term);
            }
            float ssum = 0.f;
            for (int k2 = 0; k2 < cnt2; ++k2) ssum += __expf(terms[k2] - mx);
            val = mx + __logf(ssum);
        }
        __syncthreads();
        if (act) alpha[b * T21 + t] = val;
        __syncthreads();
    }
    if (act && t == T2) p.out[b] = alpha[b * T21 + T2];
}

// ================= cooperative mega-kernel =================
__global__ void k_mega(P p) {
    __shared__ __align__(16) char smem[131072];
    cg::grid_group g = cg::this_grid();
    phase_setup(p);                       g.sync();
    phase_init_state(p, smem);            g.sync();
    phase_init2(p, smem);                 g.sync();
    phase_lstm(p, smem, -1, 0, true);     g.sync();   // L0_0 (stage resident B)
    phase_lstm(p, smem, 0, 1, false);     g.sync();   // L1_0 | L0_1
    phase_lstm(p, smem, 1, 2, false);     g.sync();
    phase_lstm(p, smem, 2, 3, false);     g.sync();
    phase_lstm(p, smem, 3, 4, false);     g.sync();
    phase_lstm(p, smem, 4, -1, false);    g.sync();   // L1_4
    phase_fc(p, smem);                    g.sync();
    phase_combine(p);                     g.sync();
    phase_dp(p, smem);
}

// fallback: one phase per regular launch (launch boundary = device sync)
__global__ void kw_phase(P p, int ph) {
    __shared__ __align__(16) char smem[131072];
    switch (ph) {
        case 0:  phase_setup(p); break;
        case 1:  phase_init_state(p, smem); break;
        case 2:  phase_init2(p, smem); break;
        case 3:  phase_lstm(p, smem, -1, 0, true); break;
        case 4:  phase_lstm(p, smem, 0, 1, true); break;
        case 5:  phase_lstm(p, smem, 1, 2, true); break;
        case 6:  phase_lstm(p, smem, 2, 3, true); break;
        case 7:  phase_lstm(p, smem, 3, 4, true); break;
        case 8:  phase_lstm(p, smem, 4, -1, true); break;
        case 9:  phase_fc(p, smem); break;
        case 10: phase_combine(p); break;
        case 11: phase_dp(p, smem); break;
    }
}

extern "C" void kernel_launch(void* const* d_in, const int* in_sizes, int n_in,
                              void* d_out, int out_size, void* d_ws, size_t ws_size,
                              hipStream_t stream) {
    P prm;
    prm.y     = (const int*)d_in[0];
    prm.enc   = (const float*)d_in[1];
    prm.embed = (const float*)d_in[2];
    prm.se    = (const float*)d_in[3];
    prm.phw   = (const float*)d_in[4];
    prm.phb   = (const float*)d_in[5];
    prm.pcw   = (const float*)d_in[6];
    prm.pcb   = (const float*)d_in[7];
    prm.wih0  = (const float*)d_in[8];
    prm.whh0  = (const float*)d_in[9];
    prm.b0    = (const float*)d_in[10];
    prm.wih1  = (const float*)d_in[11];
    prm.whh1  = (const float*)d_in[12];
    prm.b1    = (const float*)d_in[13];
    prm.fcw   = (const float*)d_in[14];
    prm.fcb   = (const float*)d_in[15];

    float* ws = (float*)d_ws;
    size_t off = 0;
    auto alloc = [&](size_t n) { float* pp = ws + off; off += n; return pp; };
    prm.projhT   = alloc((size_t)ENC * H);
    prm.projcT   = alloc((size_t)ENC * H);
    prm.ctxT     = alloc((size_t)H * G4);
    prm.xT       = alloc((size_t)E * G4);
    prm.h0       = alloc((size_t)B * T1 * H);
    prm.c0       = alloc((size_t)B * T1 * H);
    prm.pre_ctxi = alloc((size_t)B * T1 * G4);
    prm.pre_xi   = alloc((size_t)(SEG + 1) * B * T21 * G4);
    prm.c1       = alloc((size_t)NCELL * H);
    prm.c2       = alloc((size_t)NCELL * H);
    prm.b1i      = alloc((size_t)G4);
    prm.selbuf   = alloc((size_t)(SEG + 1) * NCELL);
    prm.eospbuf  = alloc((size_t)(SEG + 1) * NCELL);
    prm.psum     = alloc((size_t)NPART * MP);
    prm.hc0      = (short*)alloc((size_t)NCELL * 512 / 2);
    prm.hc1      = (short*)alloc((size_t)NCELL * 512 / 2);
    prm.h2all    = (short*)alloc(((size_t)6 * NCELL + 64) * 256 / 2);
    prm.whh0i    = (short*)alloc((size_t)G4 * 256 / 2);
    prm.w1i      = (short*)alloc((size_t)G4 * 512 / 2);
    prm.fcwbf    = (short*)alloc((size_t)V * H / 2);
    prm.out      = (float*)d_out;

    void* args[] = { (void*)&prm };
    hipError_t err = hipLaunchCooperativeKernel((const void*)k_mega, dim3(GRID), dim3(256),
                                                args, 0, stream);
    if (err != hipSuccess) {
        // fallback: same phase bodies, one launch per phase
        for (int ph = 0; ph < 12; ++ph)
            hipLaunchKernelGGL(kw_phase, dim3(GRID), dim3(256), 0, stream, prm, ph);
    }
}

// Round 12
// 173.632 us; speedup vs baseline: 3.7769x; 3.7769x over previous
//
#include <hip/hip_runtime.h>
#include <math.h>

#define B 4
#define T1 16
#define T2 16
#define SEG 4
#define V 8000
#define E 256
#define H 256
#define ENC 512
#define EOS 2
#define NEGV -1e30f
#define G4 1024
#define NCELL 1088
#define T21 17
#define NLT 544       // 34*16 lstm tiles per layer-step (32-row M tiles)
#define MP 5504       // padded batched fc rows (43*128)
#define NTM 43        // fc m-tiles (128 rows)
#define NTN 63        // fc n-tiles (128 cols)
#define NFCT (NTM*NTN) // 2709
#define NPART 126     // psum partials (63 nb * 2 wn)

typedef __attribute__((ext_vector_type(4))) float f32x4;
typedef __attribute__((ext_vector_type(8))) short bf16x8;

__device__ __forceinline__ float sigm(float x) { return 1.f / (1.f + __expf(-x)); }
__device__ __forceinline__ float ftanh(float x) { float e = __expf(2.f * x); return 1.f - 2.f / (e + 1.f); }
__device__ __forceinline__ float b2f(short x) {
    unsigned u = ((unsigned)(unsigned short)x) << 16;
    return __builtin_bit_cast(float, u);
}
__device__ __forceinline__ short f2b(float f) {
    unsigned u = __builtin_bit_cast(unsigned, f);
    unsigned r = (u + 0x7fffu + ((u >> 16) & 1u)) >> 16;
    return (short)r;
}
// two-axis bank swizzle
__device__ __forceinline__ int swz8(int row) { return (row & 7) ^ ((row & 3) << 1); }

// stage tile into LDS: rows of 512B (32 granules), linear dest + inverse-swizzled src
template<int ISSUES>
__device__ __forceinline__ void stage512(const char* g0, size_t gstrideB, int kOffB, char* lds) {
    int tid = threadIdx.x;
#pragma unroll
    for (int it = 0; it < ISSUES; ++it) {
        int chunk = it * 256 + tid;
        int row = chunk >> 5;
        int g = chunk & 31;
        const char* src = g0 + (size_t)row * gstrideB + kOffB + ((g ^ swz8(row)) << 4);
        __builtin_amdgcn_global_load_lds((const __attribute__((address_space(1))) void*)src,
                                         (__attribute__((address_space(3))) void*)(lds + chunk * 16),
                                         16, 0, 0);
    }
}
// fragment read from tile with row-stride RSB bytes
template<int RSB>
__device__ __forceinline__ bf16x8 fragT(const char* lds, int row, int g) {
    return *(const bf16x8*)(lds + row * RSB + ((g ^ swz8(row)) << 4));
}

// ---------------- fused setup (vectorized) ----------------
__global__ void k_setup(const float* __restrict__ fcw, const float* __restrict__ whh0,
                        const float* __restrict__ wih1, const float* __restrict__ whh1,
                        const float* __restrict__ phw, const float* __restrict__ pcw,
                        const float* __restrict__ wih0, const float* __restrict__ b1,
                        short* __restrict__ fcwbf, short* __restrict__ whh0i, short* __restrict__ w1i,
                        float* __restrict__ projhT, float* __restrict__ projcT,
                        float* __restrict__ ctxT, float* __restrict__ xT, float* __restrict__ b1i) {
    int bid = blockIdx.x, tid = threadIdx.x;
    if (bid < 2000) {
        int i = (bid * 256 + tid) * 4;
        float4 v = *(const float4*)&fcw[i];
        short4 o = { f2b(v.x), f2b(v.y), f2b(v.z), f2b(v.w) };
        *(short4*)&fcwbf[i] = o;
        return;
    }
    bid -= 2000;
    if (bid < 256) {
        int i = (bid * 256 + tid) * 4;
        int gp = i >> 8, k = i & 255;
        float4 v = *(const float4*)&whh0[(size_t)((gp & 3) * 256 + (gp >> 2)) * 256 + k];
        short4 o = { f2b(v.x), f2b(v.y), f2b(v.z), f2b(v.w) };
        *(short4*)&whh0i[i] = o;
        return;
    }
    bid -= 256;
    if (bid < 512) {
        int i = (bid * 256 + tid) * 4;
        int gp = i >> 9, k = i & 511;
        int g = (gp & 3) * 256 + (gp >> 2);
        const float* src = (k < 256) ? &wih1[(size_t)g * 256 + k] : &whh1[(size_t)g * 256 + (k - 256)];
        float4 v = *(const float4*)src;
        short4 o = { f2b(v.x), f2b(v.y), f2b(v.z), f2b(v.w) };
        *(short4*)&w1i[i] = o;
        return;
    }
    bid -= 512;
    if (bid < 128) {
        int i = (bid * 256 + tid) * 4;
        int k = i >> 8, r = i & 255;
        float4 o = { phw[(size_t)r * ENC + k], phw[(size_t)(r + 1) * ENC + k],
                     phw[(size_t)(r + 2) * ENC + k], phw[(size_t)(r + 3) * ENC + k] };
        *(float4*)&projhT[i] = o;
        return;
    }
    bid -= 128;
    if (bid < 128) {
        int i = (bid * 256 + tid) * 4;
        int k = i >> 8, r = i & 255;
        float4 o = { pcw[(size_t)r * ENC + k], pcw[(size_t)(r + 1) * ENC + k],
                     pcw[(size_t)(r + 2) * ENC + k], pcw[(size_t)(r + 3) * ENC + k] };
        *(float4*)&projcT[i] = o;
        return;
    }
    bid -= 128;
    if (bid < 512) {
        int i = (bid * 256 + tid) * 4;
        int g = i >> 9, k = i & 511;
        float4 v = *(const float4*)&wih0[i];
        float* base = (k < 256) ? &ctxT[(size_t)k * G4 + g] : &xT[(size_t)(k - 256) * G4 + g];
        base[0] = v.x; base[G4] = v.y; base[2 * G4] = v.z; base[3 * G4] = v.w;
        return;
    }
    bid -= 512;
    if (bid < 1) {
        float4 o = { b1[tid], b1[256 + tid], b1[512 + tid], b1[768 + tid] };
        *(float4*)&b1i[tid * 4] = o;
    }
}

// ---------------- D1: h0/c0 partials (ENC split in 4) + pre_x ----------------
// grid 596: [0,256) init_state parts; [256,596) prex rows
__global__ void k_init1(const int* __restrict__ y, const float* __restrict__ embed, const float* __restrict__ se,
                        const float* __restrict__ enc, const float* __restrict__ phT,
                        const float* __restrict__ phb, const float* __restrict__ pcT,
                        const float* __restrict__ pcb, const float* __restrict__ xT,
                        float* __restrict__ h0p, float* __restrict__ c0p, float* __restrict__ pre_xi) {
    __shared__ float sb[256];
    int bid = blockIdx.x, j = threadIdx.x;
    if (bid < 256) {
        int q = bid & 3, bi = bid >> 2;
        int b = bi / T1, i = bi % T1;
        if (j < 128) sb[j] = enc[(size_t)(i * B + b) * ENC + q * 128 + j];
        __syncthreads();
        float ha = (q == 0) ? phb[j] : 0.f;
        float ca = (q == 0) ? pcb[j] : 0.f;
        for (int e = 0; e < 128; ++e) {
            float x = sb[e];
            ha += x * phT[(size_t)(q * 128 + e) * H + j];
            ca += x * pcT[(size_t)(q * 128 + e) * H + j];
        }
        h0p[(size_t)(q * 64 + bi) * H + j] = ha;
        c0p[(size_t)(q * 64 + bi) * H + j] = ca;
        return;
    }
    int row = bid - 256;                 // (s*B + b)*T21 + t
    int s = row / (B * T21), rem = row % (B * T21);
    int b = rem / T21, t = rem % T21;
    const float* src;
    if (s == 0) src = se;
    else { int tt = t + s - 1; if (tt > 15) tt = 15; src = embed + (size_t)y[b * T2 + tt] * E; }
    sb[j] = src[j];
    __syncthreads();
    float a0 = 0, a1 = 0, a2 = 0, a3 = 0;
    for (int k = 0; k < E; ++k) {
        float x = sb[k];
        const float* w = xT + (size_t)k * G4;
        a0 += x * w[j]; a1 += x * w[256 + j]; a2 += x * w[512 + j]; a3 += x * w[768 + j];
    }
    *(float4*)&pre_xi[(size_t)row * G4 + 4 * j] = make_float4(a0, a1, a2, a3);
}

// ---------------- D2: state bcast + pre_ctx ----------------
// grid 1152: [0,1088) bcast; [1088,1152) prectx
__global__ void k_init2(const float* __restrict__ h0p, const float* __restrict__ c0p,
                        const float* __restrict__ ctxT, const float* __restrict__ b0,
                        float* __restrict__ c1, float* __restrict__ c2,
                        short* __restrict__ hcA, short* __restrict__ hcB,
                        float* __restrict__ pre_ctxi) {
    __shared__ float sb[256];
    int bid = blockIdx.x, j = threadIdx.x;
    if (bid < NCELL) {
        int cell = bid, bi = cell / T21;
        float hv = 0.f, cv = 0.f;
#pragma unroll
        for (int q = 0; q < 4; ++q) {
            hv += h0p[(size_t)(q * 64 + bi) * H + j];
            cv += c0p[(size_t)(q * 64 + bi) * H + j];
        }
        c1[(size_t)cell * H + j] = cv;
        c2[(size_t)cell * H + j] = 0.f;
        hcA[(size_t)cell * 512 + j] = f2b(hv);        // h1_{-1}
        hcB[(size_t)cell * 512 + 256 + j] = 0;        // h2_{-1}
        return;
    }
    int bi = bid - NCELL;
    float hv = 0.f;
#pragma unroll
    for (int q = 0; q < 4; ++q) hv += h0p[(size_t)(q * 64 + bi) * H + j];
    sb[j] = hv;
    __syncthreads();
    float a0 = b0[j], a1 = b0[256 + j], a2 = b0[512 + j], a3 = b0[768 + j];
    for (int k = 0; k < H; ++k) {
        float x = sb[k];
        const float* w = ctxT + (size_t)k * G4;
        a0 += x * w[j]; a1 += x * w[256 + j]; a2 += x * w[512 + j]; a3 += x * w[768 + j];
    }
    *(float4*)&pre_ctxi[(size_t)bi * G4 + 4 * j] = make_float4(a0, a1, a2, a3);
}

// ---------------- LSTM bodies: 32Mx64N tiles, LDS-staged ----------------
// wave layout: wm = wave&1 (16-row m-frag), wn2 = wave>>1 (32-col n-half); acc[2]
__device__ __forceinline__ void mma32(const char* smA, const char* smB,
                                      int wm, int wn2, int ln, int kg, f32x4 acc[2]) {
#pragma unroll
    for (int ks = 0; ks < 8; ++ks) {
        bf16x8 a = fragT<512>(smA, wm * 16 + ln, ks * 4 + kg);
#pragma unroll
        for (int nf = 0; nf < 2; ++nf) {
            bf16x8 b = fragT<512>(smB, wn2 * 32 + nf * 16 + ln, ks * 4 + kg);
            acc[nf] = __builtin_amdgcn_mfma_f32_16x16x32_bf16(a, b, acc[nf], 0, 0, 0);
        }
    }
}

__device__ __forceinline__ void lstm0_body(int step, int l, char* smA, char* smB,
        const short* __restrict__ IN, const short* __restrict__ whh0i,
        const float* __restrict__ pre_ctxi, const float* __restrict__ pre_xi,
        float* __restrict__ c1, short* __restrict__ OUT) {
    int tid = threadIdx.x;
    int wave = tid >> 6, lane = tid & 63, ln = lane & 15, kg = lane >> 4;
    int wm = wave & 1, wn2 = wave >> 1;
    int mb = l >> 4, nb = l & 15;
    int m0 = mb * 32, n0 = nb * 64;
    stage512<4>((const char*)(IN + (size_t)m0 * 512), 1024, 0, smA);     // h1_prev (32 rows)
    stage512<8>((const char*)(whh0i + (size_t)n0 * 256), 512, 0, smB);   // B (64 rows, K=256)
    __syncthreads();
    f32x4 acc[2] = {};
    mma32(smA, smB, wm, wn2, ln, kg, acc);
    __syncthreads();
    float* sg = (float*)smA;     // [32][68]
#pragma unroll
    for (int nf = 0; nf < 2; ++nf)
#pragma unroll
        for (int r = 0; r < 4; ++r)
            sg[(wm * 16 + kg * 4 + r) * 68 + wn2 * 32 + nf * 16 + ln] = acc[nf][r];
    __syncthreads();
    int jlo = nb * 16;
#pragma unroll
    for (int q2 = 0; q2 < 2; ++q2) {
        int item = q2 * 256 + tid;
        int c = item >> 4, jj = item & 15;
        int cell = m0 + c;
        int j = jlo + jj;
        float4 g = *(float4*)&sg[c * 68 + 4 * jj];
        int bi = cell / T21;
        int bb = bi >> 4;
        int t = cell % T21;
        int prow = (step * B + bb) * T21 + t;
        float4 pc = *(const float4*)&pre_ctxi[(size_t)bi * G4 + 4 * j];
        float4 px = *(const float4*)&pre_xi[(size_t)prow * G4 + 4 * j];
        float ig = g.x + pc.x + px.x, fg = g.y + pc.y + px.y;
        float gg = g.z + pc.z + px.z, og = g.w + pc.w + px.w;
        float cold = c1[(size_t)cell * H + j];
        float cn = sigm(fg) * cold + sigm(ig) * ftanh(gg);
        float hn = sigm(og) * ftanh(cn);
        c1[(size_t)cell * H + j] = cn;
        OUT[(size_t)cell * 512 + j] = f2b(hn);
    }
}

__device__ __forceinline__ void lstm1_body(int l, char* smA, char* smB,
        const short* __restrict__ IN, const short* __restrict__ w1i,
        const float* __restrict__ b1i, float* __restrict__ c2,
        short* __restrict__ slab, short* __restrict__ OUT, bool writeOUT) {
    int tid = threadIdx.x;
    int wave = tid >> 6, lane = tid & 63, ln = lane & 15, kg = lane >> 4;
    int wm = wave & 1, wn2 = wave >> 1;
    int mb = l >> 4, nb = l & 15;
    int m0 = mb * 32, n0 = nb * 64;
    f32x4 acc[2] = {};
#pragma unroll
    for (int kh = 0; kh < 2; ++kh) {
        if (kh) __syncthreads();
        stage512<4>((const char*)(IN + (size_t)m0 * 512), 1024, kh * 512, smA);
        stage512<8>((const char*)(w1i + (size_t)n0 * 512), 1024, kh * 512, smB);
        __syncthreads();
        mma32(smA, smB, wm, wn2, ln, kg, acc);
    }
    __syncthreads();
    float* sg = (float*)smA;
#pragma unroll
    for (int nf = 0; nf < 2; ++nf)
#pragma unroll
        for (int r = 0; r < 4; ++r)
            sg[(wm * 16 + kg * 4 + r) * 68 + wn2 * 32 + nf * 16 + ln] = acc[nf][r];
    __syncthreads();
    int jlo = nb * 16;
#pragma unroll
    for (int q2 = 0; q2 < 2; ++q2) {
        int item = q2 * 256 + tid;
        int c = item >> 4, jj = item & 15;
        int cell = m0 + c;
        int j = jlo + jj;
        float4 g = *(float4*)&sg[c * 68 + 4 * jj];
        float4 bv = *(const float4*)&b1i[4 * j];
        float ig = g.x + bv.x, fg = g.y + bv.y, gg = g.z + bv.z, og = g.w + bv.w;
        float cold = c2[(size_t)cell * H + j];
        float cn = sigm(fg) * cold + sigm(ig) * ftanh(gg);
        float hn = sigm(og) * ftanh(cn);
        c2[(size_t)cell * H + j] = cn;
        short hb = f2b(hn);
        slab[(size_t)cell * 256 + j] = hb;
        if (writeOUT) OUT[(size_t)cell * 512 + 256 + j] = hb;
    }
}

// merged [L1_s || L0_{s+1}]
__global__ __launch_bounds__(256, 3) void k_lstm(int s, int n_l1, int wout,
        const short* __restrict__ IN, short* __restrict__ OUT, short* __restrict__ slab,
        const short* __restrict__ whh0i, const short* __restrict__ w1i,
        const float* __restrict__ pre_ctxi, const float* __restrict__ pre_xi,
        const float* __restrict__ b1i, float* __restrict__ c1, float* __restrict__ c2) {
    __shared__ __align__(16) char smem[49152];
    char* smA = smem;            // 16 KB
    char* smB = smem + 16384;    // 32 KB
    int bx = blockIdx.x;
    if (bx < n_l1) lstm1_body(bx, smA, smB, IN, w1i, b1i, c2, slab, OUT, wout != 0);
    else lstm0_body(s + 1, bx - n_l1, smA, smB, IN, whh0i, pre_ctxi, pre_xi, c1, OUT);
}

// ---------------- fc: 128x128 tile, K=256 in 4 staged quarters, 32 KB LDS ----------------
__global__ __launch_bounds__(256, 4) void k_fc(const short* __restrict__ h2base, const short* __restrict__ Wv,
        const float* __restrict__ fcb, float* __restrict__ psum) {
    __shared__ __align__(16) char smem[32768];
    char* smA = smem;            // [128][128B] quarter
    char* smB = smem + 16384;
    int bx = blockIdx.x;
    int xcd = bx & 7, idx = bx >> 3;
    int q = NFCT >> 3, r = NFCT & 7;
    int tl = xcd * q + (xcd < r ? xcd : r) + idx;
    int nb = tl / NTM, mb = tl % NTM;     // nb-major: XCD keeps B-band L2-resident
    int m0 = mb * 128, n0 = nb * 128;
    int tid = threadIdx.x;
    int wave = tid >> 6, lane = tid & 63, ln = lane & 15, kg = lane >> 4;
    int wm = wave >> 1, wn = wave & 1;
    f32x4 acc[4][4] = {};
#pragma unroll
    for (int kq = 0; kq < 4; ++kq) {
        if (kq) __syncthreads();
#pragma unroll
        for (int it = 0; it < 4; ++it) {          // A quarter: 128 rows x 128B
            int chunk = it * 256 + tid;
            int row = chunk >> 3;
            int g = chunk & 7;
            const char* src = (const char*)(h2base + (size_t)(m0 + row) * 256)
                              + kq * 128 + ((g ^ swz8(row)) << 4);
            __builtin_amdgcn_global_load_lds((const __attribute__((address_space(1))) void*)src,
                                             (__attribute__((address_space(3))) void*)(smA + chunk * 16),
                                             16, 0, 0);
        }
#pragma unroll
        for (int it = 0; it < 4; ++it) {          // B quarter (vocab rows clamped)
            int chunk = it * 256 + tid;
            int row = chunk >> 3;
            int g = chunk & 7;
            int grow = n0 + row; if (grow > V - 1) grow = V - 1;
            const char* src = (const char*)(Wv + (size_t)grow * 256)
                              + kq * 128 + ((g ^ swz8(row)) << 4);
            __builtin_amdgcn_global_load_lds((const __attribute__((address_space(1))) void*)src,
                                             (__attribute__((address_space(3))) void*)(smB + chunk * 16),
                                             16, 0, 0);
        }
        __syncthreads();
#pragma unroll
        for (int ks = 0; ks < 2; ++ks) {
            bf16x8 a[4], b[4];
#pragma unroll
            for (int mf = 0; mf < 4; ++mf) a[mf] = fragT<128>(smA, wm * 64 + mf * 16 + ln, ks * 4 + kg);
#pragma unroll
            for (int nf = 0; nf < 4; ++nf) b[nf] = fragT<128>(smB, wn * 64 + nf * 16 + ln, ks * 4 + kg);
#pragma unroll
            for (int mf = 0; mf < 4; ++mf)
#pragma unroll
                for (int nf = 0; nf < 4; ++nf)
                    acc[mf][nf] = __builtin_amdgcn_mfma_f32_16x16x32_bf16(a[mf], b[nf], acc[mf][nf], 0, 0, 0);
        }
    }
    // epilogue: per-row exp-sums over this block's 64-col slice (wn)
    float rs[4][4];
#pragma unroll
    for (int mf = 0; mf < 4; ++mf)
#pragma unroll
        for (int r2 = 0; r2 < 4; ++r2) rs[mf][r2] = 0.f;
#pragma unroll
    for (int nf = 0; nf < 4; ++nf) {
        int col = n0 + wn * 64 + nf * 16 + ln;
        float fbn = (col < V) ? fcb[col] : NEGV;
#pragma unroll
        for (int mf = 0; mf < 4; ++mf)
#pragma unroll
            for (int r2 = 0; r2 < 4; ++r2)
                rs[mf][r2] += __expf(acc[mf][nf][r2] + fbn);
    }
#pragma unroll
    for (int mask = 1; mask < 16; mask <<= 1)
#pragma unroll
        for (int mf = 0; mf < 4; ++mf)
#pragma unroll
            for (int r2 = 0; r2 < 4; ++r2)
                rs[mf][r2] += __shfl_xor(rs[mf][r2], mask);
    if (ln == 0) {
#pragma unroll
        for (int mf = 0; mf < 4; ++mf)
#pragma unroll
            for (int r2 = 0; r2 < 4; ++r2)
                psum[(size_t)(nb * 2 + wn) * MP + m0 + wm * 64 + mf * 16 + kg * 4 + r2] = rs[mf][r2];
    }
}

// ---------------- combine: tgt/EOS dots + sum of 126 psum partials ----------------
__global__ void k_combine(const short* __restrict__ h2all, const short* __restrict__ Wv,
        const float* __restrict__ fcb, const int* __restrict__ y,
        const float* __restrict__ psum, float* __restrict__ sel, float* __restrict__ eosp) {
    int cb = blockIdx.x;                 // s*17 + blk
    int s = cb / 17, blk = cb % 17;
    int tid = threadIdx.x;
    int cl = tid >> 2, q = tid & 3;
    int cell = blk * 64 + cl;
    int b = cell / (T1 * T21);
    int t = cell % T21;
    int tv = 0;
    if (s < SEG) { int tt = t + s; if (tt > 15) tt = 15; tv = y[b * T2 + tt]; }
    const short* hp = h2all + (size_t)(s + 1) * NCELL * 256 + (size_t)cell * 256 + q * 64;
    const short* w1 = Wv + (size_t)tv * 256 + q * 64;
    const short* w2 = Wv + (size_t)EOS * 256 + q * 64;
    float d1 = 0.f, d2 = 0.f;
#pragma unroll
    for (int u = 0; u < 8; ++u) {
        bf16x8 av  = *(const bf16x8*)(hp + u * 8);
        bf16x8 wv1 = *(const bf16x8*)(w1 + u * 8);
        bf16x8 wv2 = *(const bf16x8*)(w2 + u * 8);
#pragma unroll
        for (int e = 0; e < 8; ++e) {
            float a = b2f(av[e]);
            d1 += a * b2f(wv1[e]);
            d2 += a * b2f(wv2[e]);
        }
    }
    d1 += __shfl_xor(d1, 1); d1 += __shfl_xor(d1, 2);
    d2 += __shfl_xor(d2, 1); d2 += __shfl_xor(d2, 2);
    int col = s * NCELL + cell;
    float ss = 0.f;
    for (int v2 = q * 32; v2 < q * 32 + 32 && v2 < NPART; ++v2)
        ss += psum[(size_t)v2 * MP + col];
    ss += __shfl_xor(ss, 1); ss += __shfl_xor(ss, 2);
    if (q == 0) {
        float lse = __logf(ss);
        sel[s * NCELL + cell]  = d1 + fcb[tv]  - lse;
        eosp[s * NCELL + cell] = d2 + fcb[EOS] - lse;
    }
}

// ---------------- final DP, fully LDS-resident ----------------
__global__ void k_dp(const float* __restrict__ sel, const float* __restrict__ eosp, float* __restrict__ out) {
    __shared__ float row[SEG + 1][NCELL];
    __shared__ float alpha[B][T21];
    int tid = threadIdx.x;
    for (int c = tid; c < NCELL; c += 256) {
        float cum = 0.f;
        row[0][c] = eosp[c];
#pragma unroll
        for (int j = 1; j <= SEG; ++j) {
            cum += sel[(j - 1) * NCELL + c];
            row[j][c] = cum + eosp[j * NCELL + c];
        }
    }
    int b = tid / T21, t = tid % T21;
    bool act = tid < B * T21;
    if (act) alpha[b][t] = (t == 0) ? 0.f : NEGV;
    __syncthreads();
    for (int i = 0; i < T1; ++i) {
        float val = NEGV;
        if (act) {
            float terms[SEG + 1];
            float mx = -3.4e38f;
            int cnt2 = 0;
            for (int j = 0; j <= SEG && j <= t; ++j) {
                int cell = (b * T1 + i) * T21 + (t - j);
                float term = alpha[b][t - j] + row[j][cell];
                terms[cnt2++] = term;
                mx = fmaxf(mx, term);
            }
            float ssum = 0.f;
            for (int k2 = 0; k2 < cnt2; ++k2) ssum += __expf(terms[k2] - mx);
            val = mx + __logf(ssum);
        }
        __syncthreads();
        if (act) alpha[b][t] = val;
        __syncthreads();
    }
    if (act && t == T2) out[b] = alpha[b][T2];
}

extern "C" void kernel_launch(void* const* d_in, const int* in_sizes, int n_in,
                              void* d_out, int out_size, void* d_ws, size_t ws_size,
                              hipStream_t stream) {
    const int*   y     = (const int*)d_in[0];
    const float* enc   = (const float*)d_in[1];
    const float* embed = (const float*)d_in[2];
    const float* se    = (const float*)d_in[3];
    const float* phw   = (const float*)d_in[4];
    const float* phb   = (const float*)d_in[5];
    const float* pcw   = (const float*)d_in[6];
    const float* pcb   = (const float*)d_in[7];
    const float* wih0  = (const float*)d_in[8];
    const float* whh0  = (const float*)d_in[9];
    const float* b0    = (const float*)d_in[10];
    const float* wih1  = (const float*)d_in[11];
    const float* whh1  = (const float*)d_in[12];
    const float* b1    = (const float*)d_in[13];
    const float* fcw   = (const float*)d_in[14];
    const float* fcb   = (const float*)d_in[15];

    float* ws = (float*)d_ws;
    size_t off = 0;
    auto alloc = [&](size_t n) { float* p = ws + off; off += n; return p; };
    float* projhT   = alloc((size_t)ENC * H);
    float* projcT   = alloc((size_t)ENC * H);
    float* ctxT     = alloc((size_t)H * G4);
    float* xT       = alloc((size_t)E * G4);
    float* h0p      = alloc((size_t)4 * 64 * H);
    float* c0p      = alloc((size_t)4 * 64 * H);
    float* pre_ctxi = alloc((size_t)B * T1 * G4);
    float* pre_xi   = alloc((size_t)(SEG + 1) * B * T21 * G4);
    float* c1       = alloc((size_t)NCELL * H);
    float* c2       = alloc((size_t)NCELL * H);
    float* b1i      = alloc((size_t)G4);
    float* selbuf   = alloc((size_t)(SEG + 1) * NCELL);
    float* eospbuf  = alloc((size_t)(SEG + 1) * NCELL);
    float* psum     = alloc((size_t)NPART * MP);
    short* hc0      = (short*)alloc((size_t)NCELL * 512 / 2);
    short* hc1      = (short*)alloc((size_t)NCELL * 512 / 2);
    short* h2all    = (short*)alloc(((size_t)6 * NCELL + 64) * 256 / 2);  // +pad rows
    short* whh0i    = (short*)alloc((size_t)G4 * 256 / 2);
    short* w1i      = (short*)alloc((size_t)G4 * 512 / 2);
    short* fcwbf    = (short*)alloc((size_t)V * H / 2);

    hipLaunchKernelGGL(k_setup, dim3(3537), dim3(256), 0, stream,
                       fcw, whh0, wih1, whh1, phw, pcw, wih0, b1,
                       fcwbf, whh0i, w1i, projhT, projcT, ctxT, xT, b1i);
    hipLaunchKernelGGL(k_init1, dim3(256 + (SEG + 1) * B * T21), dim3(256), 0, stream,
                       y, embed, se, enc, projhT, phb, projcT, pcb, xT, h0p, c0p, pre_xi);
    hipLaunchKernelGGL(k_init2, dim3(NCELL + 64), dim3(256), 0, stream,
                       h0p, c0p, ctxT, b0, c1, c2, hc0, hc1, pre_ctxi);

    // H_{-1}=hc0, H_0=hc1, H_1=hc0, ... (H_s = hcb[(s+1)&1])
    short* hcb[2] = { hc0, hc1 };
    // L0_0 only
    hipLaunchKernelGGL(k_lstm, dim3(NLT), dim3(256), 0, stream,
                       -1, 0, 1, hcb[0], hcb[1], h2all,
                       whh0i, w1i, pre_ctxi, pre_xi, b1i, c1, c2);
    for (int s = 0; s < SEG; ++s) {
        // [L1_s || L0_{s+1}]: IN=H_s, OUT=H_{s+1}, slab=h2all[s+1]
        hipLaunchKernelGGL(k_lstm, dim3(2 * NLT), dim3(256), 0, stream,
                           s, NLT, 1, hcb[(s + 1) & 1], hcb[s & 1],
                           h2all + (size_t)(s + 1) * NCELL * 256,
                           whh0i, w1i, pre_ctxi, pre_xi, b1i, c1, c2);
    }
    // L1_4 only (no OUT upper write needed)
    hipLaunchKernelGGL(k_lstm, dim3(NLT), dim3(256), 0, stream,
                       4, NLT, 0, hcb[1], hcb[0],
                       h2all + (size_t)5 * NCELL * 256,
                       whh0i, w1i, pre_ctxi, pre_xi, b1i, c1, c2);

    hipLaunchKernelGGL(k_fc, dim3(NFCT), dim3(256), 0, stream,
                       h2all + (size_t)NCELL * 256, fcwbf, fcb, psum);
    hipLaunchKernelGGL(k_combine, dim3(85), dim3(256), 0, stream,
                       h2all, fcwbf, fcb, y, psum, selbuf, eospbuf);
    hipLaunchKernelGGL(k_dp, dim3(1), dim3(256), 0, stream, selbuf, eospbuf, (float*)d_out);
}